// Round 3
// baseline (326.400 us; speedup 1.0000x reference)
//
#include <hip/hip_runtime.h>
#include <math.h>

// Problem constants (from reference): B=128, N=131072, D=1
#define PF_B 128
#define PF_N 131072
#define TPB 256                 // threads per block
#define EPT 8                   // elements per thread (2 x float4)
#define EPB (TPB * EPT)         // 2048 elements per block
#define BLOCKS_PER_BATCH (PF_N / EPB)   // 64

typedef float v4f __attribute__((ext_vector_type(4)));

// d_out layout: [new_particles: B*N floats][w: B*N floats]

__global__ __launch_bounds__(TPB) void pf_compute(
    const float* __restrict__ particles,
    const float* __restrict__ weights,
    const float* __restrict__ obs,        // [B]
    const float* __restrict__ noise,
    const int*   __restrict__ tstep,      // [1]
    float* __restrict__ np_out,           // [B*N]
    float* __restrict__ w_out,            // [B*N] (unnormalized after this pass)
    float* __restrict__ sums)             // [B] (pre-zeroed)
{
    const int b     = blockIdx.x / BLOCKS_PER_BATCH;
    const int chunk = blockIdx.x % BLOCKS_PER_BATCH;
    const long base = (long)b * PF_N + (long)chunk * EPB;

    const float ob     = obs[b];
    const float c      = 8.0f * cosf(1.2f * (float)(*tstep));
    const float sq10   = 3.16227770f;     // np.float32(sqrt(10))
    const float nhl2pi = -0.9189385f;     // -0.5*log(2*pi) in fp32

    float lsum = 0.0f;

    #pragma unroll
    for (int k = 0; k < EPT / 4; ++k) {
        const long idx = base + (long)k * (TPB * 4) + (long)threadIdx.x * 4;
        // Inputs are single-use: non-temporal loads keep them from evicting
        // the w_out lines we want L3 to hold for pass 2.
        const v4f x4  = __builtin_nontemporal_load((const v4f*)(particles + idx));
        const v4f n4  = __builtin_nontemporal_load((const v4f*)(noise + idx));
        const v4f wt4 = __builtin_nontemporal_load((const v4f*)(weights + idx));

        v4f xn, wn;

        #pragma unroll
        for (int j = 0; j < 4; ++j) {
            const float x = x4[j];
            // mean = x/2 + 25*x/(x^2+1) + 8*cos(1.2*t)
            const float mean = x * 0.5f + 25.0f * (x / (x * x + 1.0f)) + c;
            const float xnew = mean + n4[j] * sq10;
            xn[j] = xnew;
            const float om = (xnew * xnew) / 20.0f;
            const float d  = ob - om;
            const float lp = -0.5f * d * d + nhl2pi;
            const float wv = wt4[j] * __expf(lp);
            wn[j] = wv;
            lsum += wv;
        }

        // np is never re-read: bypass cache.
        __builtin_nontemporal_store(xn, (v4f*)(np_out + idx));
        // w IS re-read by pass 2: normal (cached) store so L3 can serve it.
        *(v4f*)(w_out + idx) = wn;
    }

    // wave (64-lane) reduction, then cross-wave via LDS, one atomic per block
    #pragma unroll
    for (int off = 32; off > 0; off >>= 1)
        lsum += __shfl_down(lsum, off, 64);

    __shared__ float red[TPB / 64];
    if ((threadIdx.x & 63) == 0) red[threadIdx.x >> 6] = lsum;
    __syncthreads();
    if (threadIdx.x == 0) {
        float s = 0.0f;
        #pragma unroll
        for (int i = 0; i < TPB / 64; ++i) s += red[i];
        atomicAdd(&sums[b], s);
    }
}

__global__ __launch_bounds__(TPB) void pf_normalize(
    float* __restrict__ w_out,
    const float* __restrict__ sums)
{
    const int b     = blockIdx.x / BLOCKS_PER_BATCH;
    const int chunk = blockIdx.x % BLOCKS_PER_BATCH;
    const long base = (long)b * PF_N + (long)chunk * EPB;
    const float inv = 1.0f / sums[b];

    #pragma unroll
    for (int k = 0; k < EPT / 4; ++k) {
        const long idx = base + (long)k * (TPB * 4) + (long)threadIdx.x * 4;
        v4f v = *(const v4f*)(w_out + idx);   // hopefully L3-hit
        v *= inv;
        // final w is never re-read: bypass cache on the way out.
        __builtin_nontemporal_store(v, (v4f*)(w_out + idx));
    }
}

extern "C" void kernel_launch(void* const* d_in, const int* in_sizes, int n_in,
                              void* d_out, int out_size, void* d_ws, size_t ws_size,
                              hipStream_t stream) {
    const float* particles = (const float*)d_in[0];
    const float* weights   = (const float*)d_in[1];
    const float* obs       = (const float*)d_in[2];
    const float* noise     = (const float*)d_in[3];
    // d_in[4] = uniforms: dead code in the reference (resample output unused)
    const int*   tstep     = (const int*)d_in[5];

    float* np_out = (float*)d_out;                     // new_particles [B*N]
    float* w_out  = (float*)d_out + (long)PF_B * PF_N; // weights      [B*N]
    float* sums   = (float*)d_ws;                      // [B]

    hipMemsetAsync(d_ws, 0, PF_B * sizeof(float), stream);

    const int grid = PF_B * BLOCKS_PER_BATCH;  // 8192 blocks
    pf_compute<<<grid, TPB, 0, stream>>>(particles, weights, obs, noise, tstep,
                                         np_out, w_out, sums);
    pf_normalize<<<grid, TPB, 0, stream>>>(w_out, sums);
}